// Round 11
// baseline (150.353 us; speedup 1.0000x reference)
//
#include <hip/hip_runtime.h>
#include <hip/hip_bf16.h>

// NLinear: out[b,f,o] = sum_i x[b,f,i] * w[f,i,o] + bias[f,o]
// B=8192, F=64, I=128, O=128, fp32.
//
// R11 = R9 EXACTLY (the 150us passing kernel: G=4 feature-grouping, 2KB/row
// DRAM granularity, single raw[16] ping-pong, constant vmcnt(16) waits)
// plus ONE delta: amdgpu_waves_per_eu(2,2). LDS (128KB) already caps us at
// 1 block/CU = 2 waves/EU, but the compiler budgeted VGPRs for 4 waves/EU
// (VGPR_Count=128) and spilled ~90 regs to scratch (R9's WRITE was 309MB vs
// 264 ideal = scratch traffic). Forcing min=max=2 unlocks the 256-reg budget.
// R10 bundled this with two other changes and failed replay-validation; this
// round isolates the variable.

#define NF 64
#define DI 128
#define DO 128
#define G 4
#define FG 16                 // feature groups
#define CHUNKS 16
#define ROWSPB 512            // rows per block
#define BMT 128               // rows per block-tile (8 waves x 16)
#define TILES 4
#define RS (NF * DI)          // 8192 floats

typedef __attribute__((ext_vector_type(8))) short short8;
typedef __attribute__((ext_vector_type(4))) float floatx4;

static __device__ __forceinline__ unsigned short f2bf(float f) {
    union { float f; unsigned u; } v; v.f = f;
    unsigned r = v.u + 0x7fffu + ((v.u >> 16) & 1u);
    return (unsigned short)(r >> 16);
}
static __device__ __forceinline__ float bflo(unsigned u) {
    union { unsigned u; float f; } v; v.u = u << 16; return v.f;
}
static __device__ __forceinline__ float bfhi(unsigned u) {
    union { unsigned u; float f; } v; v.u = u & 0xffff0000u; return v.f;
}

// 16 batched dwordx4 loads (2 features x 8), offsets fi*512 + kk*128 + h*16.
#define ISSUE16(r, p)                                                     \
    asm volatile(                                                         \
        "global_load_dwordx4 %0, %16, off\n\t"                            \
        "global_load_dwordx4 %1, %16, off offset:16\n\t"                  \
        "global_load_dwordx4 %2, %16, off offset:128\n\t"                 \
        "global_load_dwordx4 %3, %16, off offset:144\n\t"                 \
        "global_load_dwordx4 %4, %16, off offset:256\n\t"                 \
        "global_load_dwordx4 %5, %16, off offset:272\n\t"                 \
        "global_load_dwordx4 %6, %16, off offset:384\n\t"                 \
        "global_load_dwordx4 %7, %16, off offset:400\n\t"                 \
        "global_load_dwordx4 %8, %16, off offset:512\n\t"                 \
        "global_load_dwordx4 %9, %16, off offset:528\n\t"                 \
        "global_load_dwordx4 %10, %16, off offset:640\n\t"                \
        "global_load_dwordx4 %11, %16, off offset:656\n\t"                \
        "global_load_dwordx4 %12, %16, off offset:768\n\t"                \
        "global_load_dwordx4 %13, %16, off offset:784\n\t"                \
        "global_load_dwordx4 %14, %16, off offset:896\n\t"                \
        "global_load_dwordx4 %15, %16, off offset:912\n\t"                \
        : "=&v"(r[0]), "=&v"(r[1]), "=&v"(r[2]), "=&v"(r[3]),             \
          "=&v"(r[4]), "=&v"(r[5]), "=&v"(r[6]), "=&v"(r[7]),             \
          "=&v"(r[8]), "=&v"(r[9]), "=&v"(r[10]), "=&v"(r[11]),           \
          "=&v"(r[12]), "=&v"(r[13]), "=&v"(r[14]), "=&v"(r[15])          \
        : "v"(p) : "memory")

__global__ __launch_bounds__(512, 2)
__attribute__((amdgpu_waves_per_eu(2, 2)))
void nlinear_kernel(const float* __restrict__ x,
                    const float* __restrict__ w,
                    const float* __restrict__ bias,
                    float* __restrict__ out) {
    // 4 W^T panels, bf16, swizzled: (o,i) at fi*32768 + o*256 + ((i*2)^((o&15)<<4)).
    // EXACTLY 131072 bytes (the proven-launchable max; R7's +2KB failed launch).
    __shared__ unsigned short lds_wt[G * DI * DO];

    int b = blockIdx.x;
    int fg    = b >> 4;            // 0..15
    int chunk = b & 15;            // 0..15 -> XCD = chunk%8
    int g0 = fg * G;

    int tid  = threadIdx.x;
    int lane = tid & 63;
    int wid  = tid >> 6;           // 0..7
    int lrow = lane & 15;
    int kq   = lane >> 4;          // 0..3

    // ---- bias -> packed bf16 VGPRs (64 regs; uniform per quarter, L2 broadcast) ----
    unsigned bpk[G][8][2];
    {
        const float* bp = bias + (size_t)g0 * DO + kq * 4;
        #pragma unroll
        for (int fi = 0; fi < G; ++fi)
            #pragma unroll
            for (int n = 0; n < 8; ++n) {
                floatx4 v = *(const floatx4*)(bp + fi * DO + n * 16);
                bpk[fi][n][0] = (unsigned)f2bf(v[0]) | ((unsigned)f2bf(v[1]) << 16);
                bpk[fi][n][1] = (unsigned)f2bf(v[2]) | ((unsigned)f2bf(v[3]) << 16);
            }
    }

    size_t row0 = (size_t)chunk * ROWSPB + wid * 16 + lrow;
    const float* xw = x   + row0 * RS + g0 * DI + kq * 8;
    float*       ow = out + row0 * RS + g0 * DO + kq * 4;

    floatx4 raw[16];
    ISSUE16(raw, xw);              // tile 0, features 0-1: fly under W staging

    // ---- stage 4 W^T panels (paired-row b32 packed writes) ----
    #pragma unroll
    for (int fi = 0; fi < G; ++fi) {
        const float* wf = w + (size_t)(g0 + fi) * DI * DO;
        unsigned short* wt = lds_wt + fi * DI * DO;
        #pragma unroll
        for (int it = 0; it < 4; ++it) {
            int id = it * 512 + tid;       // 0..2047
            int o4 = (id & 31) << 2;
            int i  = (id >> 5) * 2;        // even k-row
            floatx4 v0 = *(const floatx4*)(wf + i * DO + o4);
            floatx4 v1 = *(const floatx4*)(wf + (i + 1) * DO + o4);
            #pragma unroll
            for (int j = 0; j < 4; ++j) {
                int o = o4 + j;
                int byte = o * 256 + ((i * 2) ^ ((o & 15) << 4));
                unsigned pk = (unsigned)f2bf(v0[j]) | ((unsigned)f2bf(v1[j]) << 16);
                *(unsigned*)((char*)wt + byte) = pk;
            }
        }
    }
    __syncthreads();
    asm volatile("s_waitcnt vmcnt(0)" ::: "memory");   // tile0-f01 loads landed
    __builtin_amdgcn_sched_barrier(0);

    // convert one feature-pair from raw into ax[0..7]
    auto convert2 = [&](short8* ax) {
        #pragma unroll
        for (int q = 0; q < 8; ++q) {      // q = fi*4 + kk
            floatx4 v0 = raw[q * 2], v1 = raw[q * 2 + 1];
            short8 a;
            a[0] = (short)f2bf(v0[0]); a[1] = (short)f2bf(v0[1]);
            a[2] = (short)f2bf(v0[2]); a[3] = (short)f2bf(v0[3]);
            a[4] = (short)f2bf(v1[0]); a[5] = (short)f2bf(v1[1]);
            a[6] = (short)f2bf(v1[2]); a[7] = (short)f2bf(v1[3]);
            ax[q] = a;
        }
    };

    #pragma unroll 1
    for (int t = 0; t < TILES; ++t) {
        const float* xt = xw + (size_t)t * BMT * RS;
        float* op = ow + (size_t)t * BMT * RS;

        short8 ax[8];

        // ===== phase A: features 0,1 =====
        // steady state outstanding: [f01 loads(16), f23 stores of t-1 (16)]
        // -> vmcnt(16) retires the loads. t=0: already drained, no-op.
        asm volatile("s_waitcnt vmcnt(16)" ::: "memory");
        __builtin_amdgcn_sched_barrier(0);
        convert2(ax);
        ISSUE16(raw, xt + 2 * DI);         // features 2-3 of tile t

        #pragma unroll
        for (int fp = 0; fp < 2; ++fp) {   // ff = fp (features 0,1)
            floatx4 acc[8];
            #pragma unroll
            for (int n = 0; n < 8; ++n) {
                acc[n][0] = bflo(bpk[fp][n][0]);
                acc[n][1] = bfhi(bpk[fp][n][0]);
                acc[n][2] = bflo(bpk[fp][n][1]);
                acc[n][3] = bfhi(bpk[fp][n][1]);
            }
            const char* wtb = (const char*)lds_wt + fp * 32768;
            #pragma unroll
            for (int kk = 0; kk < 4; ++kk) {
                int kb = (kk * 64 + kq * 16) ^ (lrow << 4);
                #pragma unroll
                for (int n = 0; n < 8; ++n) {
                    short8 bw = *(const short8*)(wtb + (n * 16 + lrow) * 256 + kb);
                    acc[n] = __builtin_amdgcn_mfma_f32_16x16x32_bf16(
                                 bw, ax[fp * 4 + kk], acc[n], 0, 0, 0);
                }
            }
            #pragma unroll
            for (int n = 0; n < 8; ++n)
                *(floatx4*)(op + fp * DO + n * 16) = acc[n];
        }

        // ===== phase B: features 2,3 =====
        // outstanding: [f23 loads(16), f01 stores(16)] -> vmcnt(16).
        asm volatile("s_waitcnt vmcnt(16)" ::: "memory");
        __builtin_amdgcn_sched_barrier(0);
        convert2(ax);
        if (t < TILES - 1)
            ISSUE16(raw, xt + (size_t)BMT * RS);   // features 0-1 of tile t+1

        #pragma unroll
        for (int fp = 0; fp < 2; ++fp) {   // ff = 2 + fp
            floatx4 acc[8];
            #pragma unroll
            for (int n = 0; n < 8; ++n) {
                acc[n][0] = bflo(bpk[2 + fp][n][0]);
                acc[n][1] = bfhi(bpk[2 + fp][n][0]);
                acc[n][2] = bflo(bpk[2 + fp][n][1]);
                acc[n][3] = bfhi(bpk[2 + fp][n][1]);
            }
            const char* wtb = (const char*)lds_wt + (2 + fp) * 32768;
            #pragma unroll
            for (int kk = 0; kk < 4; ++kk) {
                int kb = (kk * 64 + kq * 16) ^ (lrow << 4);
                #pragma unroll
                for (int n = 0; n < 8; ++n) {
                    short8 bw = *(const short8*)(wtb + (n * 16 + lrow) * 256 + kb);
                    acc[n] = __builtin_amdgcn_mfma_f32_16x16x32_bf16(
                                 bw, ax[fp * 4 + kk], acc[n], 0, 0, 0);
                }
            }
            #pragma unroll
            for (int n = 0; n < 8; ++n)
                *(floatx4*)(op + (2 + fp) * DO + n * 16) = acc[n];
        }
    }
}

extern "C" void kernel_launch(void* const* d_in, const int* in_sizes, int n_in,
                              void* d_out, int out_size, void* d_ws, size_t ws_size,
                              hipStream_t stream) {
    const float* x    = (const float*)d_in[0];
    const float* wght = (const float*)d_in[1];
    const float* bias = (const float*)d_in[2];
    float* out        = (float*)d_out;

    dim3 grid(FG * CHUNKS);   // 256 blocks, 1 per CU
    dim3 block(512);
    nlinear_kernel<<<grid, block, 0, stream>>>(x, wght, bias, out);
}